// Round 3
// baseline (473.271 us; speedup 1.0000x reference)
//
#include <hip/hip_runtime.h>

// NTuple approximator: out[b] = sum_s weights[table_ids[s], base16(boards[b, sym_coords[s]])]
// B=65536, 32 syms, weights = 4 x 16^6 fp32 = 256 MB.
//
// R1/R2: direct random gather = 339 us, occupancy-invariant -> random-line-fill
//   rate cap (~5.9 G lines/s, ~380 GB/s effective). L3 is cold every iteration
//   (1 GB ws poison evicts it).
// R3: convert random->streaming. Phase A buckets the 2M (flat_idx, board)
//   records by 32KB weight tile; Phase B streams each tile sequentially into
//   LDS and serves its ~244 records with LDS gathers + atomicAdd to out.

static constexpr int NSYM = 32;
static constexpr int TLEN = 6;

static constexpr int TILE_LOG2 = 13;                    // 8192 entries = 32 KB per tile
static constexpr int TILE      = 1 << TILE_LOG2;
static constexpr int TOTAL_ENTRIES_LOG2 = 26;           // 4 tables * 16^6 = 64M entries
static constexpr int NBUCKETS  = 1 << (TOTAL_ENTRIES_LOG2 - TILE_LOG2);  // 8192
static constexpr int CAP       = 512;                   // avg 244/bucket; 11-sigma margin

// ws layout: [0, NBUCKETS*4)           bucket counters (zeroed each launch)
//            [NBUCKETS*4, + NBUCKETS*CAP*4)  records: (board << 13) | (flat & 8191)

__global__ __launch_bounds__(256) void phaseA_bucket(
    const int* __restrict__ boards,
    const float* __restrict__ weights,
    const int* __restrict__ sym_coords,
    const int* __restrict__ table_ids,
    unsigned int* __restrict__ cnt,
    unsigned int* __restrict__ recs,
    float* __restrict__ out, int B)
{
    __shared__ int s_coords[NSYM * TLEN];
    __shared__ int s_base[NSYM];

    const int t = threadIdx.x;
    if (t < NSYM * TLEN) s_coords[t] = sym_coords[t];
    if (t < NSYM)        s_base[t]   = table_ids[t] << 24;
    __syncthreads();

    const int g = blockIdx.x * 256 + t;
    const int b = g >> 3;            // board
    const int chunk = g & 7;         // 4 syms per thread
    if (b >= B) return;

    const int4* bp = reinterpret_cast<const int4*>(boards + (size_t)b * 16);
    const int4 r0 = bp[0], r1 = bp[1], r2 = bp[2], r3 = bp[3];
    const int c[16] = {r0.x, r0.y, r0.z, r0.w, r1.x, r1.y, r1.z, r1.w,
                       r2.x, r2.y, r2.z, r2.w, r3.x, r3.y, r3.z, r3.w};
    unsigned long long packed = 0ull;
#pragma unroll
    for (int i = 0; i < 16; ++i)
        packed |= (unsigned long long)((unsigned)c[i] & 15u) << (4 * i);

#pragma unroll
    for (int k = 0; k < 4; ++k) {
        const int s = chunk * 4 + k;
        int feat = 0;
#pragma unroll
        for (int j = 0; j < TLEN; ++j) {
            const int cc = s_coords[s * TLEN + j];
            feat = (feat << 4) | (int)((packed >> (cc << 2)) & 15ull);
        }
        const unsigned flat = (unsigned)(s_base[s] + feat);
        const unsigned bucket = flat >> TILE_LOG2;
        const unsigned slot = atomicAdd(&cnt[bucket], 1u);
        if (slot < CAP) {
            recs[(size_t)bucket * CAP + slot] =
                ((unsigned)b << TILE_LOG2) | (flat & (TILE - 1u));
        } else {
            // overflow fallback (statistically never): direct gather
            atomicAdd(&out[b], weights[(size_t)flat]);
        }
    }
}

__global__ __launch_bounds__(256) void phaseB_stream(
    const float* __restrict__ weights,
    const unsigned int* __restrict__ cnt,
    const unsigned int* __restrict__ recs,
    float* __restrict__ out)
{
    __shared__ float tile[TILE];   // 32 KB -> 4 blocks/CU

    const int bid = blockIdx.x;
    const int t = threadIdx.x;

    // Sequential stream of this bucket's 32 KB weight tile into LDS.
    const float4* w4 = reinterpret_cast<const float4*>(weights + ((size_t)bid << TILE_LOG2));
    float4* t4 = reinterpret_cast<float4*>(tile);
#pragma unroll
    for (int k = 0; k < TILE / 4 / 256; ++k)      // 8 iters x 16 B/lane
        t4[k * 256 + t] = w4[k * 256 + t];
    __syncthreads();

    unsigned n = cnt[bid];
    if (n > CAP) n = CAP;
    for (unsigned i = t; i < n; i += 256) {
        const unsigned rec = recs[(size_t)bid * CAP + i];
        atomicAdd(&out[rec >> TILE_LOG2], tile[rec & (TILE - 1u)]);
    }
}

extern "C" void kernel_launch(void* const* d_in, const int* in_sizes, int n_in,
                              void* d_out, int out_size, void* d_ws, size_t ws_size,
                              hipStream_t stream) {
    const int*   boards     = (const int*)d_in[0];
    const float* weights    = (const float*)d_in[1];
    const int*   sym_coords = (const int*)d_in[2];
    const int*   table_ids  = (const int*)d_in[3];
    float*       out        = (float*)d_out;

    unsigned int* cnt  = (unsigned int*)d_ws;
    unsigned int* recs = cnt + NBUCKETS;

    const int B = in_sizes[0] / 16;

    hipMemsetAsync(out, 0, (size_t)out_size * sizeof(float), stream);
    hipMemsetAsync(cnt, 0, (size_t)NBUCKETS * sizeof(unsigned int), stream);

    const int totalA = B * 8;
    phaseA_bucket<<<(totalA + 255) / 256, 256, 0, stream>>>(
        boards, weights, sym_coords, table_ids, cnt, recs, out, B);

    phaseB_stream<<<NBUCKETS, 256, 0, stream>>>(weights, cnt, recs, out);
}

// Round 4
// 439.771 us; speedup vs baseline: 1.0762x; 1.0762x over previous
//
#include <hip/hip_runtime.h>

// NTuple approximator: out[b] = sum_s weights[table_ids[s], base16(boards[b, sym_coords[s]])]
// B=65536, 32 syms, weights = 4 x 16^6 fp32 = 256 MB.
//
// R1/R2: direct random gather = 339 us, occupancy/MLP-invariant -> bound by
//   outstanding-line-miss concurrency (~450/XCD x ~600ns => ~6G lines/s).
// R3: bucket+stream with 4M device atomics = 473 us (regression).
// R4: exact counting sort, ZERO device atomics, dense layout:
//   K1 hist -> K2 column prefix -> K3 scan -> K4 scatter (LDS rank) ->
//   K5 per-bucket LDS tile stream + serve -> K6 unsort reduce.

static constexpr int NSYM = 32;
static constexpr int TLEN = 6;
static constexpr int BLOG = 13;                  // 8192-entry (32 KB) weight buckets
static constexpr int NBUCK = 1 << (26 - BLOG);   // 8192 buckets
static constexpr int BMASK = (1 << BLOG) - 1;
static constexpr int NA = 64;                    // histogram blocks
static constexpr int BPB = 1024;                 // boards per A-block (NA*BPB = 65536)

// ---------- shared feature machinery ----------
__device__ __forceinline__ unsigned long long pack_board(const int* boards, int b) {
    const int4* bp = reinterpret_cast<const int4*>(boards + (size_t)b * 16);
    const int4 r0 = bp[0], r1 = bp[1], r2 = bp[2], r3 = bp[3];
    const int c[16] = {r0.x, r0.y, r0.z, r0.w, r1.x, r1.y, r1.z, r1.w,
                       r2.x, r2.y, r2.z, r2.w, r3.x, r3.y, r3.z, r3.w};
    unsigned long long p = 0ull;
#pragma unroll
    for (int i = 0; i < 16; ++i)
        p |= (unsigned long long)((unsigned)c[i] & 15u) << (4 * i);
    return p;
}

__device__ __forceinline__ unsigned feat_of(unsigned long long packed,
                                            const int* s_coords, const int* s_base, int s) {
    unsigned f = 0;
#pragma unroll
    for (int j = 0; j < TLEN; ++j) {
        const int cc = s_coords[s * TLEN + j];
        f = (f << 4) | (unsigned)((packed >> (cc << 2)) & 15ull);
    }
    return f + (unsigned)s_base[s];   // flat index into weights (26-bit)
}

// ---------- K1: per-block bucket histogram ----------
__global__ __launch_bounds__(1024) void k1_hist(
    const int* __restrict__ boards, const int* __restrict__ sym_coords,
    const int* __restrict__ table_ids, unsigned* __restrict__ hist)
{
    __shared__ int s_coords[NSYM * TLEN];
    __shared__ int s_base[NSYM];
    __shared__ unsigned s_cnt[NBUCK];
    const int t = threadIdx.x;
    if (t < NSYM * TLEN) s_coords[t] = sym_coords[t];
    if (t < NSYM)        s_base[t]   = table_ids[t] << 24;
#pragma unroll
    for (int k = 0; k < NBUCK / 1024; ++k) s_cnt[k * 1024 + t] = 0u;
    __syncthreads();

    const int a = blockIdx.x;
    const int b = a * BPB + t;
    const unsigned long long packed = pack_board(boards, b);
#pragma unroll
    for (int s = 0; s < NSYM; ++s) {
        const unsigned flat = feat_of(packed, s_coords, s_base, s);
        atomicAdd(&s_cnt[flat >> BLOG], 1u);
    }
    __syncthreads();
#pragma unroll
    for (int k = 0; k < NBUCK / 1024; ++k)
        hist[(size_t)a * NBUCK + k * 1024 + t] = s_cnt[k * 1024 + t];
}

// ---------- K2: in-place exclusive prefix over 'a' per bucket + totals ----------
__global__ __launch_bounds__(256) void k2_colprefix(
    unsigned* __restrict__ hist, unsigned* __restrict__ tot)
{
    __shared__ unsigned T[64 * 65];   // [jj][a], pad 65 to kill bank conflicts
    const int t = threadIdx.x;
    const int j0 = blockIdx.x * 64;
#pragma unroll
    for (int r = 0; r < 16; ++r) {
        const int idx = r * 256 + t;
        const int a = idx >> 6, jj = idx & 63;
        T[jj * 65 + a] = hist[(size_t)a * NBUCK + j0 + jj];
    }
    __syncthreads();
    if (t < 64) {
        unsigned run = 0;
#pragma unroll
        for (int a = 0; a < 64; ++a) {
            const unsigned v = T[t * 65 + a];
            T[t * 65 + a] = run;
            run += v;
        }
        tot[j0 + t] = run;
    }
    __syncthreads();
#pragma unroll
    for (int r = 0; r < 16; ++r) {
        const int idx = r * 256 + t;
        const int a = idx >> 6, jj = idx & 63;
        hist[(size_t)a * NBUCK + j0 + jj] = T[jj * 65 + a];
    }
}

// ---------- K3: single-block exclusive scan of 8192 totals -> base ----------
__global__ __launch_bounds__(256) void k3_scan(
    const unsigned* __restrict__ tot, unsigned* __restrict__ base)
{
    __shared__ unsigned s_tot[NBUCK];
    __shared__ unsigned s_w[4];
    const int t = threadIdx.x;
#pragma unroll
    for (int k = 0; k < NBUCK / 256; ++k) s_tot[k * 256 + t] = tot[k * 256 + t];
    __syncthreads();

    unsigned lsum = 0;
#pragma unroll
    for (int k = 0; k < 32; ++k) lsum += s_tot[t * 32 + k];

    // wave-level inclusive scan of the 256 lsums
    unsigned v = lsum;
    for (int d = 1; d < 64; d <<= 1) {
        unsigned u = __shfl_up(v, d, 64);
        if ((t & 63) >= d) v += u;
    }
    const int w = t >> 6;
    if ((t & 63) == 63) s_w[w] = v;
    __syncthreads();
    unsigned woff = 0;
    for (int k = 0; k < 4; ++k) if (k < w) woff += s_w[k];
    unsigned run = v - lsum + woff;   // exclusive prefix of this thread's chunk

    for (int k = 0; k < 32; ++k) {
        base[t * 32 + k] = run;
        run += s_tot[t * 32 + k];
    }
    if (t == 255) base[NBUCK] = run;  // sentinel = total records
}

// ---------- K4: scatter records to dense sorted positions ----------
__global__ __launch_bounds__(1024) void k4_scatter(
    const int* __restrict__ boards, const int* __restrict__ sym_coords,
    const int* __restrict__ table_ids, const unsigned* __restrict__ hist,
    const unsigned* __restrict__ base, unsigned short* __restrict__ offs,
    unsigned* __restrict__ pos_of)
{
    __shared__ int s_coords[NSYM * TLEN];
    __shared__ int s_base[NSYM];
    __shared__ unsigned s_cnt[NBUCK];
    const int t = threadIdx.x;
    if (t < NSYM * TLEN) s_coords[t] = sym_coords[t];
    if (t < NSYM)        s_base[t]   = table_ids[t] << 24;
#pragma unroll
    for (int k = 0; k < NBUCK / 1024; ++k) s_cnt[k * 1024 + t] = 0u;
    __syncthreads();

    const int a = blockIdx.x;
    const int b = a * BPB + t;
    const unsigned long long packed = pack_board(boards, b);
    const unsigned* hrow = hist + (size_t)a * NBUCK;
    unsigned mypos[NSYM];
#pragma unroll
    for (int s = 0; s < NSYM; ++s) {
        const unsigned flat = feat_of(packed, s_coords, s_base, s);
        const unsigned j = flat >> BLOG;
        const unsigned rank = atomicAdd(&s_cnt[j], 1u);
        const unsigned pos = base[j] + hrow[j] + rank;   // L2-hot reads
        offs[pos] = (unsigned short)(flat & BMASK);
        mypos[s] = pos;
    }
    unsigned* pp = pos_of + (size_t)b * NSYM;
#pragma unroll
    for (int s = 0; s < NSYM; ++s) pp[s] = mypos[s];
}

// ---------- K5: per-bucket tile stream + serve ----------
__global__ __launch_bounds__(256) void k5_serve(
    const float* __restrict__ weights, const unsigned* __restrict__ base,
    const unsigned short* __restrict__ offs, float* __restrict__ val)
{
    __shared__ float tile[1 << BLOG];    // 32 KB
    __shared__ unsigned s_rng[2];
    const int j = blockIdx.x;
    const int t = threadIdx.x;
    const float4* w4 = reinterpret_cast<const float4*>(weights + ((size_t)j << BLOG));
    float4* t4 = reinterpret_cast<float4*>(tile);
#pragma unroll
    for (int k = 0; k < (1 << BLOG) / 4 / 256; ++k)   // 8 x float4 per thread
        t4[k * 256 + t] = w4[k * 256 + t];
    if (t < 2) s_rng[t] = base[j + t];
    __syncthreads();
    const unsigned s0 = s_rng[0], s1 = s_rng[1];
    for (unsigned i = s0 + t; i < s1; i += 256)
        val[i] = tile[offs[i]];
}

// ---------- K6: unsort + reduce ----------
__global__ __launch_bounds__(256) void k6_reduce(
    const unsigned* __restrict__ pos_of, const float* __restrict__ val,
    float* __restrict__ out, int B)
{
    const int b = blockIdx.x * 256 + threadIdx.x;
    if (b >= B) return;
    const uint4* pp = reinterpret_cast<const uint4*>(pos_of + (size_t)b * NSYM);
    float acc = 0.0f;
#pragma unroll
    for (int k = 0; k < NSYM / 4; ++k) {
        const uint4 p = pp[k];
        acc += val[p.x];
        acc += val[p.y];
        acc += val[p.z];
        acc += val[p.w];
    }
    out[b] = acc;
}

// ---------- fallback (B != 65536): direct gather ----------
__global__ __launch_bounds__(256) void direct_kernel(
    const int* __restrict__ boards, const float* __restrict__ weights,
    const int* __restrict__ sym_coords, const int* __restrict__ table_ids,
    float* __restrict__ out, int B)
{
    __shared__ int s_coords[NSYM * TLEN];
    __shared__ int s_base[NSYM];
    const int t = threadIdx.x;
    if (t < NSYM * TLEN) s_coords[t] = sym_coords[t];
    if (t < NSYM)        s_base[t]   = table_ids[t] << 24;
    __syncthreads();
    const int b = blockIdx.x * 256 + t;
    if (b >= B) return;
    const unsigned long long packed = pack_board(boards, b);
    float acc = 0.0f;
#pragma unroll
    for (int s = 0; s < NSYM; ++s)
        acc += weights[(size_t)feat_of(packed, s_coords, s_base, s)];
    out[b] = acc;
}

extern "C" void kernel_launch(void* const* d_in, const int* in_sizes, int n_in,
                              void* d_out, int out_size, void* d_ws, size_t ws_size,
                              hipStream_t stream) {
    const int*   boards     = (const int*)d_in[0];
    const float* weights    = (const float*)d_in[1];
    const int*   sym_coords = (const int*)d_in[2];
    const int*   table_ids  = (const int*)d_in[3];
    float*       out        = (float*)d_out;
    const int B = in_sizes[0] / 16;

    if (B != NA * BPB) {   // safety net; bench uses B = 65536
        direct_kernel<<<(B + 255) / 256, 256, 0, stream>>>(
            boards, weights, sym_coords, table_ids, out, B);
        return;
    }

    const int NREC = B * NSYM;                         // 2,097,152
    // ws layout (all sub-arrays 16B-aligned):
    char* w = (char*)d_ws;
    unsigned*       hist   = (unsigned*)w;              w += (size_t)NA * NBUCK * 4;   // 2 MB
    unsigned*       tot    = (unsigned*)w;              w += (size_t)NBUCK * 4;        // 32 KB
    unsigned*       base   = (unsigned*)w;              w += (size_t)(NBUCK + 4) * 4;  // 32 KB + pad
    unsigned short* offs   = (unsigned short*)w;        w += (size_t)NREC * 2;         // 4 MB
    unsigned*       pos_of = (unsigned*)w;              w += (size_t)NREC * 4;         // 8 MB
    float*          val    = (float*)w;                                                // 8 MB

    k1_hist   <<<NA,        1024, 0, stream>>>(boards, sym_coords, table_ids, hist);
    k2_colprefix<<<NBUCK/64, 256, 0, stream>>>(hist, tot);
    k3_scan   <<<1,          256, 0, stream>>>(tot, base);
    k4_scatter<<<NA,        1024, 0, stream>>>(boards, sym_coords, table_ids,
                                               hist, base, offs, pos_of);
    k5_serve  <<<NBUCK,      256, 0, stream>>>(weights, base, offs, val);
    k6_reduce <<<(B+255)/256,256, 0, stream>>>(pos_of, val, out, B);
}